// Round 2
// baseline (502.921 us; speedup 1.0000x reference)
//
#include <hip/hip_runtime.h>

constexpr int BLOCK = 256;
constexpr int B_   = 4;
constexpr int C_   = 64;      // feature channels
constexpr int N_   = 32768;
constexpr int K_   = 16;      // neighbor dim in memory
constexpr int CIN  = 68;      // 64 feat + 3 diff + 1 dist
constexpr int C1   = 128;
constexpr int C2   = 64;
constexpr int C3   = 64;
constexpr int P_   = 32;      // points per block
constexpr int NCOL = 96;      // 3 * P_

// ---------------- generic register-tiled layer: out = relu(Wt^T in + b) ----
// in:  LDS [CI][NCOL], wt: LDS [CI][CO] (BN-folded), bf: LDS [CO]
// each thread computes a COT x COLT tile of the [CO][NCOL] output.
template<int CI, int CO, int COT, int COLT>
__device__ __forceinline__ void mlp_layer(const float* __restrict__ in,
                                          const float* __restrict__ wt,
                                          const float* __restrict__ bf,
                                          float* __restrict__ outb, int tid)
{
    constexpr int NXT = NCOL / COLT;
    static_assert((CO / COT) * NXT == BLOCK, "tile grid must equal block");
    const int tx = tid % NXT;
    const int ty = tid / NXT;
    const int co0  = ty * COT;
    const int col0 = tx * COLT;

    float acc[COT][COLT];
#pragma unroll
    for (int j = 0; j < COT; ++j)
#pragma unroll
        for (int c = 0; c < COLT; ++c) acc[j][c] = 0.0f;

    for (int ci = 0; ci < CI; ++ci) {
        float w[COT], x[COLT];
#pragma unroll
        for (int j = 0; j < COT; ++j) w[j] = wt[ci * CO + co0 + j];
#pragma unroll
        for (int c = 0; c < COLT; ++c) x[c] = in[ci * NCOL + col0 + c];
#pragma unroll
        for (int j = 0; j < COT; ++j)
#pragma unroll
            for (int c = 0; c < COLT; ++c)
                acc[j][c] = fmaf(w[j], x[c], acc[j][c]);
    }
#pragma unroll
    for (int j = 0; j < COT; ++j) {
        const float bb = bf[co0 + j];
#pragma unroll
        for (int c = 0; c < COLT; ++c)
            outb[(co0 + j) * NCOL + col0 + c] = fmaxf(acc[j][c] + bb, 0.0f);
    }
}

__global__ __launch_bounds__(BLOCK, 1)
void mvp_fused(const float* __restrict__ src, const float* __restrict__ tgt,
               const float* __restrict__ feat,
               const float* __restrict__ W1, const float* __restrict__ b1,
               const float* __restrict__ g1, const float* __restrict__ be1,
               const float* __restrict__ W2, const float* __restrict__ b2,
               const float* __restrict__ g2, const float* __restrict__ be2,
               const float* __restrict__ W3, const float* __restrict__ b3,
               const float* __restrict__ g3, const float* __restrict__ be3,
               float* __restrict__ out)
{
    __shared__ float w1t[CIN * C1];   // [ci][co], BN-folded
    __shared__ float w2t[C1 * C2];
    __shared__ float w3t[C2 * C3];
    __shared__ float bf1[C1], bf2[C2], bf3[C3];
    __shared__ float bufA[CIN * NCOL];  // x, then h2
    __shared__ float bufB[C1 * NCOL];   // h1

    const int tid = threadIdx.x;
    const int b   = blockIdx.x >> 10;            // N_/P_ = 1024 blocks per batch
    const int n0  = (blockIdx.x & 1023) * P_;
    const float RS = rsqrtf(1.0f + 1e-5f);

    // ---- stage BN-folded transposed weights into LDS ----
    for (int idx = tid; idx < CIN * C1; idx += BLOCK) {
        const int ci = idx >> 7, co = idx & 127;
        w1t[idx] = W1[co * CIN + ci] * (g1[co] * RS);
    }
    for (int idx = tid; idx < C1 * C2; idx += BLOCK) {
        const int ci = idx >> 6, co = idx & 63;
        w2t[idx] = W2[co * C1 + ci] * (g2[co] * RS);
    }
    for (int idx = tid; idx < C2 * C3; idx += BLOCK) {
        const int ci = idx >> 6, co = idx & 63;
        w3t[idx] = W3[co * C2 + ci] * (g3[co] * RS);
    }
    if (tid < C1) bf1[tid] = b1[tid] * (g1[tid] * RS) + be1[tid];
    if (tid < C2) bf2[tid] = b2[tid] * (g2[tid] * RS) + be2[tid];
    if (tid < C3) bf3[tid] = b3[tid] * (g3[tid] * RS) + be3[tid];

    // ---- stage input columns: x = [feature(:, :3); diff_xyz; dist] ----
    // feature rows are 16 floats; we need k=0..2 -> one aligned float4 load.
    for (int idx = tid; idx < C_ * P_; idx += BLOCK) {
        const int c = idx >> 5, lp = idx & 31;
        const float4 f = *reinterpret_cast<const float4*>(
            feat + ((size_t)(b * C_ + c) * N_ + (n0 + lp)) * K_);
        float* dst = bufA + c * NCOL + lp * 3;
        dst[0] = f.x; dst[1] = f.y; dst[2] = f.z;
    }
    if (tid < NCOL) {
        const int lp = tid / 3, k = tid % 3;
        const int n = n0 + lp;
        const float dx = src[((size_t)(b * 3 + 0) * N_ + n) * K_ + k]
                       - tgt[(size_t)(b * 3 + 0) * N_ + n];
        const float dy = src[((size_t)(b * 3 + 1) * N_ + n) * K_ + k]
                       - tgt[(size_t)(b * 3 + 1) * N_ + n];
        const float dz = src[((size_t)(b * 3 + 2) * N_ + n) * K_ + k]
                       - tgt[(size_t)(b * 3 + 2) * N_ + n];
        bufA[(C_ + 0) * NCOL + tid] = dx;
        bufA[(C_ + 1) * NCOL + tid] = dy;
        bufA[(C_ + 2) * NCOL + tid] = dz;
        bufA[(C_ + 3) * NCOL + tid] = dx * dx + dy * dy + dz * dz;
    }
    __syncthreads();

    // ---- layer 1: 68 -> 128 ----
    mlp_layer<CIN, C1, 4, 12>(bufA, w1t, bf1, bufB, tid);
    __syncthreads();

    // ---- layer 2: 128 -> 64 ----
    mlp_layer<C1, C2, 2, 12>(bufB, w2t, bf2, bufA, tid);
    __syncthreads();

    // ---- layer 3: 64 -> 64, fused relu + neighbor-sum + store ----
    {
        constexpr int COT = 2, COLT = 12, NXT = NCOL / COLT;  // 2co x 4 points
        const int tx = tid % NXT;
        const int ty = tid / NXT;
        const int co0  = ty * COT;
        const int col0 = tx * COLT;

        float acc[COT][COLT];
#pragma unroll
        for (int j = 0; j < COT; ++j)
#pragma unroll
            for (int c = 0; c < COLT; ++c) acc[j][c] = 0.0f;

        for (int ci = 0; ci < C2; ++ci) {
            float w[COT], x[COLT];
#pragma unroll
            for (int j = 0; j < COT; ++j) w[j] = w3t[ci * C3 + co0 + j];
#pragma unroll
            for (int c = 0; c < COLT; ++c) x[c] = bufA[ci * NCOL + col0 + c];
#pragma unroll
            for (int j = 0; j < COT; ++j)
#pragma unroll
                for (int c = 0; c < COLT; ++c)
                    acc[j][c] = fmaf(w[j], x[c], acc[j][c]);
        }

        const int p0 = tx * 4;  // col0/3: 12 cols = 4 points
#pragma unroll
        for (int j = 0; j < COT; ++j) {
            const float bb = bf3[co0 + j];
            float4 o;
            o.x = fmaxf(acc[j][0] + bb, 0.f) + fmaxf(acc[j][1]  + bb, 0.f) + fmaxf(acc[j][2]  + bb, 0.f);
            o.y = fmaxf(acc[j][3] + bb, 0.f) + fmaxf(acc[j][4]  + bb, 0.f) + fmaxf(acc[j][5]  + bb, 0.f);
            o.z = fmaxf(acc[j][6] + bb, 0.f) + fmaxf(acc[j][7]  + bb, 0.f) + fmaxf(acc[j][8]  + bb, 0.f);
            o.w = fmaxf(acc[j][9] + bb, 0.f) + fmaxf(acc[j][10] + bb, 0.f) + fmaxf(acc[j][11] + bb, 0.f);
            *reinterpret_cast<float4*>(
                out + (size_t)(b * C3 + co0 + j) * N_ + n0 + p0) = o;
        }
    }
}

extern "C" void kernel_launch(void* const* d_in, const int* in_sizes, int n_in,
                              void* d_out, int out_size, void* d_ws, size_t ws_size,
                              hipStream_t stream) {
    const float* src  = (const float*)d_in[0];
    const float* tgt  = (const float*)d_in[1];
    const float* feat = (const float*)d_in[2];
    const float* W1 = (const float*)d_in[3];
    const float* b1 = (const float*)d_in[4];
    const float* g1 = (const float*)d_in[5];
    const float* be1= (const float*)d_in[6];
    const float* W2 = (const float*)d_in[7];
    const float* b2 = (const float*)d_in[8];
    const float* g2 = (const float*)d_in[9];
    const float* be2= (const float*)d_in[10];
    const float* W3 = (const float*)d_in[11];
    const float* b3 = (const float*)d_in[12];
    const float* g3 = (const float*)d_in[13];
    const float* be3= (const float*)d_in[14];
    float* out = (float*)d_out;

    const int grid = B_ * (N_ / P_);  // 4096
    mvp_fused<<<grid, BLOCK, 0, stream>>>(src, tgt, feat,
                                          W1, b1, g1, be1,
                                          W2, b2, g2, be2,
                                          W3, b3, g3, be3, out);
}